// Round 2
// baseline (248.197 us; speedup 1.0000x reference)
//
#include <hip/hip_runtime.h>
#include <math.h>

#define THREADS 256
// ===== DIAGNOSTIC AMPLIFIER (round 1) =====
// Repeat the per-thread COMPUTE 8x inside the kernel (loads/stores once,
// asm keep-alives prevent cross-rep CSE/hoisting). Makes the kernel a
// single ~8x-compute dispatch so it tops the rocprof table and exposes
// VALUBusy / Occupancy / VGPR_Count / FETCH / WRITE for the first time.
// Strip (REP=1, remove asm) once counters are read.
#define REP 8

// 32 magnitude patterns of the D4 codebook, 2-bit codes per coordinate:
// c in {0,1,2}  =>  |g_i| = 0.5 + c.   mc = c0 | c1<<2 | c2<<4 | c3<<6
// Pattern order is exactly the reference's i8 = 0..31 enumeration.
// Score identity: s_p = (A-1) + sum_{c_i=1}(2a_i-2) + sum_{c_i=2}(4a_i-6).
#define MCP_LIST \
  0x00, 0x55, 0x50, 0x05, 0x44, 0x11, 0x14, 0x41, \
  0x01, 0x04, 0x10, 0x40, 0x54, 0x51, 0x45, 0x15, \
  0x02, 0x08, 0x20, 0x80, 0x09, 0x06, 0x12, 0x42, \
  0x21, 0x24, 0x18, 0x48, 0x81, 0x84, 0x90, 0x60

__device__ const unsigned d_MCP[32] = { MCP_LIST };   // runtime-indexed copy
constexpr unsigned h_MCP[32] = { MCP_LIST };           // compile-time folded copy

__global__ __launch_bounds__(THREADS)
void d4_fused_kernel(const float* __restrict__ X,
                     const float* __restrict__ grid,
                     const float* __restrict__ gnorm,
                     float* __restrict__ out, int n)
{
    // Stage codebook for the (rare) exact slow path; broadcast reads later.
    __shared__ float4 sgrid[256];
    __shared__ float  sgn[256];
    sgrid[threadIdx.x] = reinterpret_cast<const float4*>(grid)[threadIdx.x];
    sgn[threadIdx.x]   = gnorm[threadIdx.x];
    __syncthreads();

    const int i = blockIdx.x * blockDim.x + threadIdx.x;
    if (i >= n) return;

    const float4 xv = reinterpret_cast<const float4*>(X)[i];

    float gx, gy, gz, gw, fidx;   // results, stored once after the rep loop

#pragma unroll 1
    for (int rep = 0; rep < REP; ++rep) {
        float fx0 = xv.x, fx1 = xv.y, fx2 = xv.z, fx3 = xv.w;
        // opaque copy: forces full recompute each rep, loads stay hoisted
        asm volatile("" : "+v"(fx0), "+v"(fx1), "+v"(fx2), "+v"(fx3));

        const float a0 = fabsf(fx0), a1 = fabsf(fx1), a2 = fabsf(fx2), a3 = fabsf(fx3);
        // exact: u = 2a, v = 4a
        const float r0 = (a0 + a0) - 2.f, r1 = (a1 + a1) - 2.f;
        const float r2 = (a2 + a2) - 2.f, r3 = (a3 + a3) - 2.f;
        const float z0 = (a0 + a0 + a0 + a0) - 6.f, z1 = (a1 + a1 + a1 + a1) - 6.f;
        const float z2 = (a2 + a2 + a2 + a2) - 6.f, z3 = (a3 + a3 + a3 + a3) - 6.f;
        const float A = (a0 + a1) + (a2 + a3);
        const float base = A - 1.f;

        // magnitude-weighted "flip costs" m_i * a_i for the 3 levels
        const float h0 = 0.5f * a0, h1 = 0.5f * a1, h2 = 0.5f * a2, h3 = 0.5f * a3;
        const float t0 = h0 + a0, t1 = h1 + a1, t2 = h2 + a2, t3 = h3 + a3;  // 1.5a
        const float w0 = t0 + a0, w1 = t1 + a1, w2 = t2 + a2, w3 = t3 + a3;  // 2.5a

        const int s0 = (fx0 < 0.f) ? 1 : 0, s1 = (fx1 < 0.f) ? 1 : 0;
        const int s2 = (fx2 < 0.f) ? 1 : 0, s3 = (fx3 < 0.f) ? 1 : 0;
        const int qp = (s0 + s1 + s2 + s3) & 1;   // parity of # negative coords

        // parity-penalty factors: penalty applies when rp != qp
        //   rp==0 patterns: eff = s + nA*minp ;  rp==1: eff = s + nB*minp
        const float nA = qp ? -4.f : 0.f;
        const float nB = qp ? 0.f : -4.f;

        float best = -1e30f, second = -1e30f;
        int bi = 0;
#pragma unroll
        for (int p = 0; p < 32; ++p) {
            const unsigned mc = h_MCP[p];
            const int c0 = mc & 3, c1 = (mc >> 2) & 3, c2 = (mc >> 4) & 3, c3 = (mc >> 6) & 3;

            float s = base;
            if (c0 == 1) s += r0; else if (c0 == 2) s += z0;
            if (c1 == 1) s += r1; else if (c1 == 2) s += z1;
            if (c2 == 1) s += r2; else if (c2 == 2) s += z2;
            if (c3 == 1) s += r3; else if (c3 == 2) s += z3;

            const float q0 = (c0 == 0) ? h0 : ((c0 == 1) ? t0 : w0);
            const float q1 = (c1 == 0) ? h1 : ((c1 == 1) ? t1 : w1);
            const float q2 = (c2 == 0) ? h2 : ((c2 == 1) ? t2 : w2);
            const float q3 = (c3 == 0) ? h3 : ((c3 == 1) ? t3 : w3);
            const float minp = fminf(fminf(q0, q1), fminf(q2, q3));

            const int rp = (c0 + c1 + c2 + c3) & 1;    // compile-time
            const float eff = fmaf(minp, rp ? nB : nA, s);

            // branch-free top-2 + index (exact; first-wins on ties via strict >)
            const bool gt = eff > best;
            bi = gt ? p : bi;
            second = fmaxf(second, fminf(eff, best));
            best = fmaxf(best, eff);
        }

        // ---- reconstruct winning codeword + its reference index ----
        const unsigned mc = d_MCP[bi];
        const int c0 = mc & 3, c1 = (mc >> 2) & 3, c2 = (mc >> 4) & 3, c3 = (mc >> 6) & 3;
        const int rp = (c0 + c1 + c2 + c3) & 1;
        const bool flip = (rp != qp);

        const float p0 = (c0 == 0) ? h0 : ((c0 == 1) ? t0 : w0);
        const float p1 = (c1 == 0) ? h1 : ((c1 == 1) ? t1 : w1);
        const float p2 = (c2 == 0) ? h2 : ((c2 == 1) ? t2 : w2);
        const float p3 = (c3 == 0) ? h3 : ((c3 == 1) ? t3 : w3);
        int f = 0; float mp = p0;
        if (p1 < mp) { mp = p1; f = 1; }
        if (p2 < mp) { mp = p2; f = 2; }
        if (p3 < mp) { mp = p3; f = 3; }

        // two smallest of {p0..p3} (for the within-pattern runner-up bound)
        const float m01 = fminf(p0, p1), M01 = fmaxf(p0, p1);
        const float m23 = fminf(p2, p3), M23 = fmaxf(p2, p3);
        const float q1v = fminf(m01, m23);
        const float q2v = fminf(fmaxf(m01, m23), fminf(M01, M23));

        // runner-up within the winning pattern:
        //  parity mismatch: second-best single flip  -> cost gap 4*(q2-q1)
        //  parity match:    cheapest double flip     -> cost 4*(q1+q2)
        const float within = flip ? 4.f * (q2v - q1v) : 4.f * (q1v + q2v);
        const float gap = fminf(best - second, within);
        // covers worst-case f32 rounding of BOTH my scores and the numpy
        // reference's (each <= ~7e-7*(5A+27)); >2x safety margin
        const float delta = 8e-6f * (A + 6.f);

        const bool n0 = ((s0 != 0) != (flip && f == 0));
        const bool n1 = ((s1 != 0) != (flip && f == 1));
        const bool n2 = ((s2 != 0) != (flip && f == 2));
        const bool n3 = ((s3 != 0) != (flip && f == 3));

        const float m0 = 0.5f + (float)c0, m1 = 0.5f + (float)c1;
        const float m2 = 0.5f + (float)c2, m3 = 0.5f + (float)c3;
        float rx = n0 ? -m0 : m0;
        float ry = n1 ? -m1 : m1;
        float rz = n2 ? -m2 : m2;
        float rw = n3 ? -m3 : m3;

        // invert _code3_signs: b7=sign(g0), b6=sign(g1)^b7, b5=sign(g2)^b7
        const int b7 = n0 ? 1 : 0;
        const int b6 = (n1 ? 1 : 0) ^ b7;
        const int b5 = (n2 ? 1 : 0) ^ b7;
        int idx = bi | (b5 << 5) | (b6 << 6) | (b7 << 7);

        if (gap < delta) {
            // Rare (~2e-4): bit-exact emulation of the numpy reference.
            // Sequential f32 dot (no FMA), 2*dot - gn, first-wins argmax.
            float bexact = -INFINITY;
            int bk = 0;
            for (int k = 0; k < 256; ++k) {
                const float4 gk = sgrid[k];
                float d = __fmul_rn(fx0, gk.x);
                d = __fadd_rn(d, __fmul_rn(fx1, gk.y));
                d = __fadd_rn(d, __fmul_rn(fx2, gk.z));
                d = __fadd_rn(d, __fmul_rn(fx3, gk.w));
                const float sc = __fsub_rn(__fmul_rn(2.0f, d), sgn[k]);
                if (sc > bexact) { bexact = sc; bk = k; }
            }
            const float4 ge = sgrid[bk];
            rx = ge.x; ry = ge.y; rz = ge.z; rw = ge.w;
            idx = bk;
        }

        gx = rx; gy = ry; gz = rz; gw = rw;
        fidx = (float)idx;
        // consume results each rep so reps can't be dead-code-eliminated
        asm volatile("" : "+v"(gx), "+v"(gy), "+v"(gz), "+v"(gw), "+v"(fidx));
    }

    float4 g; g.x = gx; g.y = gy; g.z = gz; g.w = gw;
    reinterpret_cast<float4*>(out)[i] = g;                 // output 0
    out[(size_t)4 * (size_t)n + (size_t)i] = fidx;         // output 1
}

extern "C" void kernel_launch(void* const* d_in, const int* in_sizes, int n_in,
                              void* d_out, int out_size, void* d_ws, size_t ws_size,
                              hipStream_t stream)
{
    const float* X = (const float*)d_in[0];
    const float* grid = (const float*)d_in[1];
    const float* gnorm = (const float*)d_in[2];
    float* out = (float*)d_out;
    const int n = in_sizes[0] / 4;
    const int blocks = (n + THREADS - 1) / THREADS;
    hipLaunchKernelGGL(d4_fused_kernel, dim3(blocks), dim3(THREADS), 0, stream,
                       X, grid, gnorm, out, n);
}

// Round 3
// 92.350 us; speedup vs baseline: 2.6876x; 2.6876x over previous
//
#include <hip/hip_runtime.h>
#include <math.h>

#define THREADS 256

// 32 magnitude patterns of the D4 codebook, 2-bit codes per coordinate:
// c in {0,1,2}  =>  |g_i| = 0.5 + c.   mc = c0 | c1<<2 | c2<<4 | c3<<6
// Pattern order is exactly the reference's i8 = 0..31 enumeration.
// Score identity: s_p = (A-1) + sum_{c_i=1}(2a_i-2) + sum_{c_i=2}(4a_i-6).
#define MCP_LIST \
  0x00, 0x55, 0x50, 0x05, 0x44, 0x11, 0x14, 0x41, \
  0x01, 0x04, 0x10, 0x40, 0x54, 0x51, 0x45, 0x15, \
  0x02, 0x08, 0x20, 0x80, 0x09, 0x06, 0x12, 0x42, \
  0x21, 0x24, 0x18, 0x48, 0x81, 0x84, 0x90, 0x60

__device__ const unsigned d_MCP[32] = { MCP_LIST };   // staged to LDS at block init
constexpr unsigned h_MCP[32] = { MCP_LIST };           // compile-time folded copy

struct FastRes {
    float gx, gy, gz, gw;   // codeword (fast-path result)
    float fidx;             // reference index as float
    bool  slow;             // route to bit-exact slow path?
};

// Straight-line fast path: no branches, so two instances interleave freely
// in the scheduler (the whole point of 2-vec/thread ILP).
__device__ __forceinline__ FastRes fast_eval(float fx0, float fx1, float fx2, float fx3,
                                             const unsigned* __restrict__ smcp)
{
    const float a0 = fabsf(fx0), a1 = fabsf(fx1), a2 = fabsf(fx2), a3 = fabsf(fx3);
    // exact: u = 2a, v = 4a
    const float r0 = (a0 + a0) - 2.f, r1 = (a1 + a1) - 2.f;
    const float r2 = (a2 + a2) - 2.f, r3 = (a3 + a3) - 2.f;
    const float z0 = (a0 + a0 + a0 + a0) - 6.f, z1 = (a1 + a1 + a1 + a1) - 6.f;
    const float z2 = (a2 + a2 + a2 + a2) - 6.f, z3 = (a3 + a3 + a3 + a3) - 6.f;
    const float A = (a0 + a1) + (a2 + a3);
    const float base = A - 1.f;

    // magnitude-weighted "flip costs" m_i * a_i for the 3 levels
    const float h0 = 0.5f * a0, h1 = 0.5f * a1, h2 = 0.5f * a2, h3 = 0.5f * a3;
    const float t0 = h0 + a0, t1 = h1 + a1, t2 = h2 + a2, t3 = h3 + a3;  // 1.5a
    const float w0 = t0 + a0, w1 = t1 + a1, w2 = t2 + a2, w3 = t3 + a3;  // 2.5a

    const int s0 = (fx0 < 0.f) ? 1 : 0, s1 = (fx1 < 0.f) ? 1 : 0;
    const int s2 = (fx2 < 0.f) ? 1 : 0, s3 = (fx3 < 0.f) ? 1 : 0;
    const int qp = (s0 + s1 + s2 + s3) & 1;   // parity of # negative coords

    // parity-penalty factors: penalty applies when rp != qp
    //   rp==0 patterns: eff = s + nA*minp ;  rp==1: eff = s + nB*minp
    const float nA = qp ? -4.f : 0.f;
    const float nB = qp ? 0.f : -4.f;

    float best = -1e30f, second = -1e30f;
    int bi = 0;
#pragma unroll
    for (int p = 0; p < 32; ++p) {
        const unsigned mc = h_MCP[p];
        const int c0 = mc & 3, c1 = (mc >> 2) & 3, c2 = (mc >> 4) & 3, c3 = (mc >> 6) & 3;

        float s = base;
        if (c0 == 1) s += r0; else if (c0 == 2) s += z0;
        if (c1 == 1) s += r1; else if (c1 == 2) s += z1;
        if (c2 == 1) s += r2; else if (c2 == 2) s += z2;
        if (c3 == 1) s += r3; else if (c3 == 2) s += z3;

        // compile-time register picks (free)
        const float q0 = (c0 == 0) ? h0 : ((c0 == 1) ? t0 : w0);
        const float q1 = (c1 == 0) ? h1 : ((c1 == 1) ? t1 : w1);
        const float q2 = (c2 == 0) ? h2 : ((c2 == 1) ? t2 : w2);
        const float q3 = (c3 == 0) ? h3 : ((c3 == 1) ? t3 : w3);
        // left-leaning chain fuses to v_min3 + v_min (2 ops vs 3)
        const float minp = fminf(fminf(fminf(q0, q1), q2), q3);

        const int rp = (c0 + c1 + c2 + c3) & 1;    // compile-time
        const float eff = fmaf(minp, rp ? nB : nA, s);

        // branch-free top-2 + index (exact; first-wins on ties via strict >)
        // med3(best, second, eff) == new runner-up given second <= best:
        //   eff>=best -> best ; second<=eff<=best -> eff ; eff<second -> second
        const bool gt = eff > best;
        bi = gt ? p : bi;
        second = __builtin_amdgcn_fmed3f(best, second, eff);
        best = fmaxf(best, eff);
    }

    // ---- reconstruct winning codeword + its reference index ----
    const unsigned mc = smcp[bi];
    const int c0 = mc & 3, c1 = (mc >> 2) & 3, c2 = (mc >> 4) & 3, c3 = (mc >> 6) & 3;
    const int rp = (c0 + c1 + c2 + c3) & 1;
    const bool flip = (rp != qp);

    const float p0 = (c0 == 0) ? h0 : ((c0 == 1) ? t0 : w0);
    const float p1 = (c1 == 0) ? h1 : ((c1 == 1) ? t1 : w1);
    const float p2 = (c2 == 0) ? h2 : ((c2 == 1) ? t2 : w2);
    const float p3 = (c3 == 0) ? h3 : ((c3 == 1) ? t3 : w3);
    int f = 0; float mp = p0;
    if (p1 < mp) { mp = p1; f = 1; }
    if (p2 < mp) { mp = p2; f = 2; }
    if (p3 < mp) { mp = p3; f = 3; }

    // two smallest of {p0..p3} (for the within-pattern runner-up bound)
    const float m01 = fminf(p0, p1), M01 = fmaxf(p0, p1);
    const float m23 = fminf(p2, p3), M23 = fmaxf(p2, p3);
    const float q1v = fminf(m01, m23);
    const float q2v = fminf(fmaxf(m01, m23), fminf(M01, M23));

    // runner-up within the winning pattern:
    //  parity mismatch: second-best single flip  -> cost gap 4*(q2-q1)
    //  parity match:    cheapest double flip     -> cost 4*(q1+q2)
    const float within = flip ? 4.f * (q2v - q1v) : 4.f * (q1v + q2v);
    const float gap = fminf(best - second, within);
    // covers worst-case f32 rounding of BOTH my scores and the numpy
    // reference's (each <= ~7e-7*(5A+27)); >2x safety margin
    const float delta = 8e-6f * (A + 6.f);

    const bool n0 = ((s0 != 0) != (flip && f == 0));
    const bool n1 = ((s1 != 0) != (flip && f == 1));
    const bool n2 = ((s2 != 0) != (flip && f == 2));
    const bool n3 = ((s3 != 0) != (flip && f == 3));

    const float m0 = 0.5f + (float)c0, m1 = 0.5f + (float)c1;
    const float m2 = 0.5f + (float)c2, m3 = 0.5f + (float)c3;

    // invert _code3_signs: b7=sign(g0), b6=sign(g1)^b7, b5=sign(g2)^b7
    const int b7 = n0 ? 1 : 0;
    const int b6 = (n1 ? 1 : 0) ^ b7;
    const int b5 = (n2 ? 1 : 0) ^ b7;

    FastRes res;
    res.gx = n0 ? -m0 : m0;
    res.gy = n1 ? -m1 : m1;
    res.gz = n2 ? -m2 : m2;
    res.gw = n3 ? -m3 : m3;
    res.fidx = (float)(bi | (b5 << 5) | (b6 << 6) | (b7 << 7));
    res.slow = (gap < delta);
    return res;
}

// Rare (~2e-4): bit-exact emulation of the numpy reference.
// Sequential f32 dot (no FMA), 2*dot - gn, first-wins argmax.
__device__ __noinline__ void exact_scan(float fx0, float fx1, float fx2, float fx3,
                                        const float4* __restrict__ sgrid,
                                        const float* __restrict__ sgn,
                                        FastRes* r)
{
    float bexact = -INFINITY;
    int bk = 0;
    for (int k = 0; k < 256; ++k) {
        const float4 gk = sgrid[k];
        float d = __fmul_rn(fx0, gk.x);
        d = __fadd_rn(d, __fmul_rn(fx1, gk.y));
        d = __fadd_rn(d, __fmul_rn(fx2, gk.z));
        d = __fadd_rn(d, __fmul_rn(fx3, gk.w));
        const float sc = __fsub_rn(__fmul_rn(2.0f, d), sgn[k]);
        if (sc > bexact) { bexact = sc; bk = k; }
    }
    const float4 ge = sgrid[bk];
    r->gx = ge.x; r->gy = ge.y; r->gz = ge.z; r->gw = ge.w;
    r->fidx = (float)bk;
}

__global__ __launch_bounds__(THREADS)
void d4_fused_kernel(const float* __restrict__ X,
                     const float* __restrict__ grid,
                     const float* __restrict__ gnorm,
                     float* __restrict__ out, int n)
{
    // Stage codebook for the (rare) exact slow path; broadcast reads later.
    __shared__ float4 sgrid[256];
    __shared__ float  sgn[256];
    __shared__ unsigned smcp[32];
    sgrid[threadIdx.x] = reinterpret_cast<const float4*>(grid)[threadIdx.x];
    sgn[threadIdx.x]   = gnorm[threadIdx.x];
    if (threadIdx.x < 32) smcp[threadIdx.x] = d_MCP[threadIdx.x];
    __syncthreads();

    // 2 vectors per thread: thread t handles t and t+half.
    // Every load/store instruction stays perfectly lane-contiguous.
    const int half = (n + 1) >> 1;
    const int t = blockIdx.x * blockDim.x + threadIdx.x;
    if (t >= half) return;

    const float4 xa = reinterpret_cast<const float4*>(X)[t];
    const int i1 = t + half;
    const bool has2 = (i1 < n);
    const float4 xb = has2 ? reinterpret_cast<const float4*>(X)[i1] : xa;

    // Two independent straight-line pipelines, adjacent so the scheduler
    // can interleave them (2-way ILP hides the fmax/med3 dep chains).
    FastRes ra = fast_eval(xa.x, xa.y, xa.z, xa.w, smcp);
    FastRes rb = fast_eval(xb.x, xb.y, xb.z, xb.w, smcp);

    // Divergent fixups AFTER both fast paths (rare: ~2e-4 per vector).
    if (ra.slow) exact_scan(xa.x, xa.y, xa.z, xa.w, sgrid, sgn, &ra);
    if (rb.slow) exact_scan(xb.x, xb.y, xb.z, xb.w, sgrid, sgn, &rb);

    float4 g; g.x = ra.gx; g.y = ra.gy; g.z = ra.gz; g.w = ra.gw;
    reinterpret_cast<float4*>(out)[t] = g;                 // output 0
    out[(size_t)4 * (size_t)n + (size_t)t] = ra.fidx;      // output 1
    if (has2) {
        float4 g2; g2.x = rb.gx; g2.y = rb.gy; g2.z = rb.gz; g2.w = rb.gw;
        reinterpret_cast<float4*>(out)[i1] = g2;
        out[(size_t)4 * (size_t)n + (size_t)i1] = rb.fidx;
    }
}

extern "C" void kernel_launch(void* const* d_in, const int* in_sizes, int n_in,
                              void* d_out, int out_size, void* d_ws, size_t ws_size,
                              hipStream_t stream)
{
    const float* X = (const float*)d_in[0];
    const float* grid = (const float*)d_in[1];
    const float* gnorm = (const float*)d_in[2];
    float* out = (float*)d_out;
    const int n = in_sizes[0] / 4;
    const int half = (n + 1) >> 1;
    const int blocks = (half + THREADS - 1) / THREADS;
    hipLaunchKernelGGL(d4_fused_kernel, dim3(blocks), dim3(THREADS), 0, stream,
                       X, grid, gnorm, out, n);
}